// Round 3
// baseline (523.864 us; speedup 1.0000x reference)
//
#include <hip/hip_runtime.h>
#include <hip/hip_bf16.h>
#include <stdint.h>

// HiPPO-LegT LTI scan: c_t = dA c_{t-1} + dB u_t, out = all c_t. N=256, L=4096, B=64.
// Structure:
//   c[k*64+dt] = dA^{dt+1} . s_k  +  sum_{p<=dt} (dA^p dB) . u[k*64+dt-p]   (main_gemm, MFMA)
//   s_k via Kogge-Stone over chunk finals with batched MFMA GEMM levels:
//   g^{(0)}=f;  g_k += M^{2^d} g_{k-2^d}  (d=0..5, M=dA^64)  =>  s_k = g_{k-1}.
// All fp32 data; MFMA operands split bf16 hi/lo (3-MFMA products, rel err ~2^-17).

#define N 256
#define LSEQ 4096
#define BATCH 64
#define TCH 64
#define NCH 64

using bf16x8 = __attribute__((ext_vector_type(8))) __bf16;
using f32x4  = __attribute__((ext_vector_type(4))) float;

__device__ __forceinline__ unsigned short f2bf(float f) {
  uint32_t x = __builtin_bit_cast(uint32_t, f);
  uint32_t r = x + 0x7fffu + ((x >> 16) & 1u);
  return (unsigned short)(r >> 16);
}
__device__ __forceinline__ float bf2f(unsigned short h) {
  uint32_t x = ((uint32_t)h) << 16;
  return __builtin_bit_cast(float, x);
}

// prep0: bid<64 -> transpose u (L x B) into uT (B x L); bid>=64 -> copy dA into power
// slot 0 (dA^1) and write its bf16 hi/lo split.
__global__ __launch_bounds__(256) void prep0(const float* __restrict__ u,
                                             const float* __restrict__ dA,
                                             float* __restrict__ uT,
                                             float* __restrict__ Pw,
                                             unsigned short* __restrict__ Phi,
                                             unsigned short* __restrict__ Plo) {
  __shared__ float tile[64][65];
  int bid = blockIdx.x, tid = threadIdx.x;
  if (bid < 64) {
    int t0 = bid * 64;
    #pragma unroll
    for (int q = 0; q < 16; ++q) {
      int e = q * 256 + tid;
      int tt = e >> 6, b = e & 63;
      tile[b][tt] = u[(size_t)(t0 + tt) * 64 + b];
    }
    __syncthreads();
    #pragma unroll
    for (int q = 0; q < 16; ++q) {
      int e = q * 256 + tid;
      int b = e >> 6, tt = e & 63;
      uT[(size_t)b * 4096 + t0 + tt] = tile[b][tt];
    }
  } else {
    int base = (bid - 64) * 1024 + tid * 4;
    float4 v = *(const float4*)&dA[base];
    *(float4*)&Pw[base] = v;
    float vv[4] = {v.x, v.y, v.z, v.w};
    #pragma unroll
    for (int q = 0; q < 4; ++q) {
      unsigned short h = f2bf(vv[q]);
      Phi[base + q] = h;
      Plo[base + q] = f2bf(vv[q] - bf2f(h));
    }
  }
}

// pow_level: for q=1..half: P[half+q] = P[q] @ P[half] (slots are m-1). fp32 + hi/lo.
__global__ __launch_bounds__(256) void pow_level(float* __restrict__ Pw,
                                                 unsigned short* __restrict__ Phi,
                                                 unsigned short* __restrict__ Plo,
                                                 int half) {
  __shared__ float As[64][17];
  __shared__ float Bs[16][64];
  int q = blockIdx.y + 1;
  const float* A = Pw + (size_t)(q - 1) * 65536;
  const float* B = Pw + (size_t)(half - 1) * 65536;
  size_t co = (size_t)(half + q - 1) * 65536;
  int bx = blockIdx.x;
  int gr0 = (bx >> 2) * 64, gc0 = (bx & 3) * 64;
  int tid = threadIdx.x;
  int ty = tid >> 4, tx = tid & 15;

  float acc[4][4];
  #pragma unroll
  for (int r = 0; r < 4; ++r)
    #pragma unroll
    for (int c = 0; c < 4; ++c) acc[r][c] = 0.f;

  for (int k0 = 0; k0 < 256; k0 += 16) {
    {
      int r = tid >> 2, c4 = (tid & 3) * 4;
      float4 va = *(const float4*)&A[(size_t)(gr0 + r) * 256 + k0 + c4];
      As[r][c4] = va.x; As[r][c4 + 1] = va.y; As[r][c4 + 2] = va.z; As[r][c4 + 3] = va.w;
      int kk = tid >> 4, c4b = (tid & 15) * 4;
      *(float4*)&Bs[kk][c4b] = *(const float4*)&B[(size_t)(k0 + kk) * 256 + gc0 + c4b];
    }
    __syncthreads();
    #pragma unroll
    for (int kk = 0; kk < 16; ++kk) {
      float a0 = As[ty * 4 + 0][kk], a1 = As[ty * 4 + 1][kk];
      float a2 = As[ty * 4 + 2][kk], a3 = As[ty * 4 + 3][kk];
      float b0 = Bs[kk][tx * 4 + 0], b1 = Bs[kk][tx * 4 + 1];
      float b2 = Bs[kk][tx * 4 + 2], b3 = Bs[kk][tx * 4 + 3];
      acc[0][0] += a0 * b0; acc[0][1] += a0 * b1; acc[0][2] += a0 * b2; acc[0][3] += a0 * b3;
      acc[1][0] += a1 * b0; acc[1][1] += a1 * b1; acc[1][2] += a1 * b2; acc[1][3] += a1 * b3;
      acc[2][0] += a2 * b0; acc[2][1] += a2 * b1; acc[2][2] += a2 * b2; acc[2][3] += a2 * b3;
      acc[3][0] += a3 * b0; acc[3][1] += a3 * b1; acc[3][2] += a3 * b2; acc[3][3] += a3 * b3;
    }
    __syncthreads();
  }
  #pragma unroll
  for (int r = 0; r < 4; ++r)
    #pragma unroll
    for (int c = 0; c < 4; ++c) {
      size_t idx = co + (size_t)(gr0 + ty * 4 + r) * 256 + gc0 + tx * 4 + c;
      float v = acc[r][c];
      Pw[idx] = v;
      unsigned short h = f2bf(v);
      Phi[idx] = h;
      Plo[idx] = f2bf(v - bf2f(h));
    }
}

// sq_mm: C = A @ A (256x256 fp32), also writes bf16 hi/lo of C. Grid 16 blocks.
__global__ __launch_bounds__(256) void sq_mm(const float* __restrict__ A,
                                             float* __restrict__ C,
                                             unsigned short* __restrict__ Chi,
                                             unsigned short* __restrict__ Clo) {
  __shared__ float As[64][17];
  __shared__ float Bs[16][64];
  int bx = blockIdx.x;
  int gr0 = (bx >> 2) * 64, gc0 = (bx & 3) * 64;
  int tid = threadIdx.x;
  int ty = tid >> 4, tx = tid & 15;

  float acc[4][4];
  #pragma unroll
  for (int r = 0; r < 4; ++r)
    #pragma unroll
    for (int c = 0; c < 4; ++c) acc[r][c] = 0.f;

  for (int k0 = 0; k0 < 256; k0 += 16) {
    {
      int r = tid >> 2, c4 = (tid & 3) * 4;
      float4 va = *(const float4*)&A[(size_t)(gr0 + r) * 256 + k0 + c4];
      As[r][c4] = va.x; As[r][c4 + 1] = va.y; As[r][c4 + 2] = va.z; As[r][c4 + 3] = va.w;
      int kk = tid >> 4, c4b = (tid & 15) * 4;
      *(float4*)&Bs[kk][c4b] = *(const float4*)&A[(size_t)(k0 + kk) * 256 + gc0 + c4b];
    }
    __syncthreads();
    #pragma unroll
    for (int kk = 0; kk < 16; ++kk) {
      float a0 = As[ty * 4 + 0][kk], a1 = As[ty * 4 + 1][kk];
      float a2 = As[ty * 4 + 2][kk], a3 = As[ty * 4 + 3][kk];
      float b0 = Bs[kk][tx * 4 + 0], b1 = Bs[kk][tx * 4 + 1];
      float b2 = Bs[kk][tx * 4 + 2], b3 = Bs[kk][tx * 4 + 3];
      acc[0][0] += a0 * b0; acc[0][1] += a0 * b1; acc[0][2] += a0 * b2; acc[0][3] += a0 * b3;
      acc[1][0] += a1 * b0; acc[1][1] += a1 * b1; acc[1][2] += a1 * b2; acc[1][3] += a1 * b3;
      acc[2][0] += a2 * b0; acc[2][1] += a2 * b1; acc[2][2] += a2 * b2; acc[2][3] += a2 * b3;
      acc[3][0] += a3 * b0; acc[3][1] += a3 * b1; acc[3][2] += a3 * b2; acc[3][3] += a3 * b3;
    }
    __syncthreads();
  }
  #pragma unroll
  for (int r = 0; r < 4; ++r)
    #pragma unroll
    for (int c = 0; c < 4; ++c) {
      size_t idx = (size_t)(gr0 + ty * 4 + r) * 256 + gc0 + tx * 4 + c;
      float v = acc[r][c];
      C[idx] = v;
      unsigned short h = f2bf(v);
      Chi[idx] = h;
      Clo[idx] = f2bf(v - bf2f(h));
    }
}

// make_K: K[p] = dA^p dB (K[0]=dB).
__global__ __launch_bounds__(256) void make_K(const float* __restrict__ Pw,
                                              const float* __restrict__ dB,
                                              float* __restrict__ Kf,
                                              unsigned short* __restrict__ Khi,
                                              unsigned short* __restrict__ Klo) {
  int p = blockIdx.x, tid = threadIdx.x, lane = tid & 63, w = tid >> 6;
  if (p == 0) {
    float v = dB[tid];
    Kf[tid] = v;
    unsigned short h = f2bf(v);
    Khi[tid] = h;
    Klo[tid] = f2bf(v - bf2f(h));
    return;
  }
  const float* M = Pw + (size_t)(p - 1) * 65536;
  float d0 = dB[lane], d1 = dB[lane + 64], d2 = dB[lane + 128], d3 = dB[lane + 192];
  for (int ii = 0; ii < 64; ++ii) {
    int i = w * 64 + ii;
    const float* row = M + (size_t)i * 256;
    float acc = row[lane] * d0 + row[lane + 64] * d1 + row[lane + 128] * d2 + row[lane + 192] * d3;
    #pragma unroll
    for (int off = 32; off; off >>= 1) acc += __shfl_xor(acc, off, 64);
    if (lane == 0) {
      Kf[p * 256 + i] = acc;
      unsigned short h = f2bf(acc);
      Khi[p * 256 + i] = h;
      Klo[p * 256 + i] = f2bf(acc - bf2f(h));
    }
  }
}

// make_MT (fallback path only)
__global__ __launch_bounds__(256) void make_MT(const float* __restrict__ Pw,
                                               float* __restrict__ MT) {
  int j = blockIdx.x, i = threadIdx.x;
  MT[(size_t)j * 256 + i] = Pw[(size_t)63 * 65536 + (size_t)i * 256 + j];
}

// finals: G0[k][b][i] = sum_p K[p][i]*u[k*64+63-p][b]  (= g^(0)_k, zero-init chunk-end states)
__global__ __launch_bounds__(256) void finals(const float* __restrict__ K,
                                              const float* __restrict__ u,
                                              float* __restrict__ f) {
  int k = blockIdx.x, b = blockIdx.y, i = threadIdx.x;
  float acc = 0.f;
  int ubase = (k * TCH + 63) * BATCH + b;
  #pragma unroll 8
  for (int p = 0; p < TCH; ++p)
    acc += K[p * N + i] * u[ubase - p * BATCH];
  f[(k * BATCH + b) * N + i] = acc;
}

// ks_level: one Kogge-Stone level. Gout[m] = Gin[m] + Gin[m - shiftRows] @ M^T
// (rows m=(k,b), cols i; M given as hi/lo bf16 row-major [i][j]).
// Rows below shiftRows stage zero A-fragments -> pure copy falls out.
__global__ __launch_bounds__(256, 2) void ks_level(const float* __restrict__ Gin,
                                                   float* __restrict__ Gout,
                                                   const unsigned short* __restrict__ Mh,
                                                   const unsigned short* __restrict__ Ml,
                                                   int shiftRows) {
  __shared__ unsigned short Ah[128 * 40], Al[128 * 40], Bh[128 * 40], Bl[128 * 40];
  int x = blockIdx.x;
  int it = x & 1, kbt = x >> 1;
  int kb0 = kbt * 128, i0 = it * 128;
  int tid = threadIdx.x, lane = tid & 63, wid = tid >> 6;
  int wr = wid >> 1, wc = wid & 1;
  int rg = lane >> 4, cl = lane & 15;

  // C-init = Gin (the "+ G[k]" term, exact fp32)
  f32x4 acc[4][4];
  #pragma unroll
  for (int mf = 0; mf < 4; ++mf) {
    int rb = kb0 + wr * 64 + mf * 16 + rg * 4;
    #pragma unroll
    for (int nf = 0; nf < 4; ++nf) {
      int i = i0 + wc * 64 + nf * 16 + cl;
      #pragma unroll
      for (int r = 0; r < 4; ++r)
        acc[mf][nf][r] = Gin[(size_t)(rb + r) * 256 + i];
    }
  }

  for (int kt = 0; kt < 8; ++kt) {
    int r = tid >> 1, h = tid & 1;
    int co = kt * 32 + h * 16;
    int lo_ = r * 40 + h * 16;
    // A: shifted Gin rows, fp32 -> hi/lo (zeros when shifted out of range)
    int srow = kb0 + r - shiftRows;
    if (srow >= 0) {
      const float* src = &Gin[(size_t)srow * 256 + co];
      #pragma unroll
      for (int qq = 0; qq < 16; qq += 4) {
        float4 v = *(const float4*)(src + qq);
        float vv[4] = {v.x, v.y, v.z, v.w};
        #pragma unroll
        for (int e = 0; e < 4; ++e) {
          unsigned short hh = f2bf(vv[e]);
          Ah[lo_ + qq + e] = hh;
          Al[lo_ + qq + e] = f2bf(vv[e] - bf2f(hh));
        }
      }
    } else {
      #pragma unroll
      for (int qq = 0; qq < 16; ++qq) { Ah[lo_ + qq] = 0; Al[lo_ + qq] = 0; }
    }
    // B: M rows [i0+r][co..]
    const unsigned short* mb = &Mh[(size_t)(i0 + r) * 256 + co];
    const unsigned short* ml2 = &Ml[(size_t)(i0 + r) * 256 + co];
    *(uint4*)&Bh[lo_]     = *(const uint4*)mb;
    *(uint4*)&Bh[lo_ + 8] = *(const uint4*)(mb + 8);
    *(uint4*)&Bl[lo_]     = *(const uint4*)ml2;
    *(uint4*)&Bl[lo_ + 8] = *(const uint4*)(ml2 + 8);
    __syncthreads();

    int kseg = lane >> 4, fr = lane & 15;
    bf16x8 ah[4], al[4], bh[4], bl[4];
    #pragma unroll
    for (int mf = 0; mf < 4; ++mf) {
      int row = (wr * 64 + mf * 16 + fr) * 40 + kseg * 8;
      ah[mf] = *(const bf16x8*)&Ah[row];
      al[mf] = *(const bf16x8*)&Al[row];
    }
    #pragma unroll
    for (int nf = 0; nf < 4; ++nf) {
      int row = (wc * 64 + nf * 16 + fr) * 40 + kseg * 8;
      bh[nf] = *(const bf16x8*)&Bh[row];
      bl[nf] = *(const bf16x8*)&Bl[row];
    }
    #pragma unroll
    for (int mf = 0; mf < 4; ++mf)
      #pragma unroll
      for (int nf = 0; nf < 4; ++nf) {
        acc[mf][nf] = __builtin_amdgcn_mfma_f32_16x16x32_bf16(ah[mf], bh[nf], acc[mf][nf], 0, 0, 0);
        acc[mf][nf] = __builtin_amdgcn_mfma_f32_16x16x32_bf16(ah[mf], bl[nf], acc[mf][nf], 0, 0, 0);
        acc[mf][nf] = __builtin_amdgcn_mfma_f32_16x16x32_bf16(al[mf], bh[nf], acc[mf][nf], 0, 0, 0);
      }
    __syncthreads();
  }

  #pragma unroll
  for (int mf = 0; mf < 4; ++mf) {
    int rb = kb0 + wr * 64 + mf * 16 + rg * 4;
    #pragma unroll
    for (int nf = 0; nf < 4; ++nf) {
      int i = i0 + wc * 64 + nf * 16 + cl;
      #pragma unroll
      for (int r = 0; r < 4; ++r)
        Gout[(size_t)(rb + r) * 256 + i] = acc[mf][nf][r];
    }
  }
}

// split_carr: shi/slo[k][b][i] = k==0 ? 0 : split(G[k-1][b][i])
__global__ __launch_bounds__(256) void split_carr(const float* __restrict__ G,
                                                  unsigned short* __restrict__ shi,
                                                  unsigned short* __restrict__ slo) {
  int k = blockIdx.x, tid = threadIdx.x;
  size_t base = (size_t)k * 16384;
  for (int e = tid; e < 16384; e += 256) {
    float v = (k == 0) ? 0.f : G[base - 16384 + e];
    unsigned short h = f2bf(v);
    shi[base + e] = h;
    slo[base + e] = f2bf(v - bf2f(h));
  }
}

// scan (fallback path only): serial fp32 carry scan.
__global__ __launch_bounds__(512) void scan(const float* __restrict__ MT,
                                            const float* __restrict__ f,
                                            unsigned short* __restrict__ shi,
                                            unsigned short* __restrict__ slo) {
  __shared__ float sbuf[256];
  __shared__ float psum[256];
  int b = blockIdx.x, tid = threadIdx.x;
  int i = tid & 255, jh = tid >> 8;
  if (tid < 256) sbuf[i] = 0.f;
  __syncthreads();
  for (int k = 0; k < NCH; ++k) {
    if (jh == 0) {
      float v = sbuf[i];
      unsigned short h = f2bf(v);
      size_t o = (size_t)(k * BATCH + b) * 256 + i;
      shi[o] = h;
      slo[o] = f2bf(v - bf2f(h));
    }
    if (k == NCH - 1) break;
    float acc = 0.f;
    int j0 = jh * 128;
    #pragma unroll 8
    for (int j = 0; j < 128; ++j)
      acc += MT[(size_t)(j0 + j) * 256 + i] * sbuf[j0 + j];
    __syncthreads();
    if (jh == 1) psum[i] = acc;
    __syncthreads();
    if (jh == 0) sbuf[i] = acc + psum[i] + f[(size_t)(k * BATCH + b) * 256 + i];
    __syncthreads();
  }
}

// main_gemm: out[k*64+dt][b][i] = sum_j P[dt+1][i][j] s_k[b][j] + sum_{p<=dt} K[p][i] u[kT+dt-p][b]
__global__ __launch_bounds__(256, 2) void main_gemm(const unsigned short* __restrict__ shi,
                                                    const unsigned short* __restrict__ slo,
                                                    const unsigned short* __restrict__ Phi,
                                                    const unsigned short* __restrict__ Plo,
                                                    const unsigned short* __restrict__ Khi,
                                                    const unsigned short* __restrict__ Klo,
                                                    const float* __restrict__ uT,
                                                    float* __restrict__ out) {
  __shared__ unsigned short Ah[128 * 40], Al[128 * 40], Bh[128 * 40], Bl[128 * 40];
  int dt = blockIdx.y;
  int x = blockIdx.x;
  int it = x >> 5, kbt = x & 31;
  int kb0 = kbt * 128, i0 = it * 128;
  int tid = threadIdx.x;
  int lane = tid & 63, wid = tid >> 6;
  int wr = wid >> 1, wc = wid & 1;

  f32x4 acc[4][4];
  #pragma unroll
  for (int mf = 0; mf < 4; ++mf)
    #pragma unroll
    for (int nf = 0; nf < 4; ++nf)
      #pragma unroll
      for (int r = 0; r < 4; ++r) acc[mf][nf][r] = 0.f;

  const unsigned short* PhiD = Phi + (size_t)dt * 65536;
  const unsigned short* PloD = Plo + (size_t)dt * 65536;
  int nkt = (dt >= 32) ? 10 : 9;

  for (int kt = 0; kt < nkt; ++kt) {
    int r = tid >> 1, h = tid & 1;
    if (kt < 8) {
      int co = kt * 32 + h * 16;
      const unsigned short* p1 = shi + (size_t)(kb0 + r) * 256 + co;
      const unsigned short* p2 = slo + (size_t)(kb0 + r) * 256 + co;
      const unsigned short* p3 = PhiD + (size_t)(i0 + r) * 256 + co;
      const unsigned short* p4 = PloD + (size_t)(i0 + r) * 256 + co;
      int lo_ = r * 40 + h * 16;
      *(uint4*)&Ah[lo_]     = *(const uint4*)p1;
      *(uint4*)&Ah[lo_ + 8] = *(const uint4*)(p1 + 8);
      *(uint4*)&Al[lo_]     = *(const uint4*)p2;
      *(uint4*)&Al[lo_ + 8] = *(const uint4*)(p2 + 8);
      *(uint4*)&Bh[lo_]     = *(const uint4*)p3;
      *(uint4*)&Bh[lo_ + 8] = *(const uint4*)(p3 + 8);
      *(uint4*)&Bl[lo_]     = *(const uint4*)p4;
      *(uint4*)&Bl[lo_ + 8] = *(const uint4*)(p4 + 8);
    } else {
      int p0 = (kt - 8) * 32;
      int kk = (kb0 + r) >> 6, b = (kb0 + r) & 63;
      const float* ub2 = uT + (size_t)b * 4096 + kk * 64 + dt;
      #pragma unroll
      for (int qq = 0; qq < 16; ++qq) {
        int pp = h * 16 + qq;
        int sh = p0 + pp;
        float v = (sh <= dt) ? ub2[-sh] : 0.f;
        unsigned short hv = f2bf(v);
        Ah[r * 40 + pp] = hv;
        Al[r * 40 + pp] = f2bf(v - bf2f(hv));
      }
      int n = tid & 127, ph = tid >> 7;
      #pragma unroll
      for (int qq = 0; qq < 16; ++qq) {
        int pp = ph * 16 + qq;
        Bh[n * 40 + pp] = Khi[(p0 + pp) * 256 + i0 + n];
        Bl[n * 40 + pp] = Klo[(p0 + pp) * 256 + i0 + n];
      }
    }
    __syncthreads();

    int kseg = lane >> 4, fr = lane & 15;
    bf16x8 ah[4], al[4], bh[4], bl[4];
    #pragma unroll
    for (int mf = 0; mf < 4; ++mf) {
      int row = (wr * 64 + mf * 16 + fr) * 40 + kseg * 8;
      ah[mf] = *(const bf16x8*)&Ah[row];
      al[mf] = *(const bf16x8*)&Al[row];
    }
    #pragma unroll
    for (int nf = 0; nf < 4; ++nf) {
      int row = (wc * 64 + nf * 16 + fr) * 40 + kseg * 8;
      bh[nf] = *(const bf16x8*)&Bh[row];
      bl[nf] = *(const bf16x8*)&Bl[row];
    }
    #pragma unroll
    for (int mf = 0; mf < 4; ++mf)
      #pragma unroll
      for (int nf = 0; nf < 4; ++nf) {
        acc[mf][nf] = __builtin_amdgcn_mfma_f32_16x16x32_bf16(ah[mf], bh[nf], acc[mf][nf], 0, 0, 0);
        acc[mf][nf] = __builtin_amdgcn_mfma_f32_16x16x32_bf16(ah[mf], bl[nf], acc[mf][nf], 0, 0, 0);
        acc[mf][nf] = __builtin_amdgcn_mfma_f32_16x16x32_bf16(al[mf], bh[nf], acc[mf][nf], 0, 0, 0);
      }
    __syncthreads();
  }

  int rg = lane >> 4, cl = lane & 15;
  #pragma unroll
  for (int mf = 0; mf < 4; ++mf) {
    int kbrow_base = kb0 + wr * 64 + mf * 16 + rg * 4;
    #pragma unroll
    for (int nf = 0; nf < 4; ++nf) {
      int i = i0 + wc * 64 + nf * 16 + cl;
      #pragma unroll
      for (int r = 0; r < 4; ++r) {
        int kbrow = kbrow_base + r;
        int k = kbrow >> 6, b = kbrow & 63;
        size_t t = (size_t)(k * 64 + dt);
        out[(t * 64 + b) * 256 + i] = acc[mf][nf][r];
      }
    }
  }
}

// ======================= HOST =======================

extern "C" void kernel_launch(void* const* d_in, const int* in_sizes, int n_in,
                              void* d_out, int out_size, void* d_ws, size_t ws_size,
                              hipStream_t stream) {
  (void)in_sizes; (void)n_in; (void)out_size;
  const float* u  = (const float*)d_in[0];
  const float* dA = (const float*)d_in[1];
  const float* dB = (const float*)d_in[2];
  float* out = (float*)d_out;
  char* ws = (char*)d_ws;

  // common layout
  float*          Pw  = (float*)(ws + 0);                  // 16 MB: dA^1..dA^64 (slot m-1)
  unsigned short* Phi = (unsigned short*)(ws + 16777216);  // 8 MB
  unsigned short* Plo = (unsigned short*)(ws + 25165824);  // 8 MB
  float*          Kf  = (float*)(ws + 33554432);           // 64 KB
  unsigned short* Khi = (unsigned short*)(ws + 33619968);  // 32 KB
  unsigned short* Klo = (unsigned short*)(ws + 33652736);  // 32 KB
  unsigned short* shi = (unsigned short*)(ws + 33685504);  // 2 MB
  unsigned short* slo = (unsigned short*)(ws + 35782656);  // 2 MB
  float*          G0  = (float*)(ws + 37879808);           // 4 MB
  float*          uT  = (float*)(ws + 42074112);           // 1 MB

  const size_t NEED_KS = 44433408;
  const size_t NEED_R1 = 43384832;

  prep0<<<128, 256, 0, stream>>>(u, dA, uT, Pw, Phi, Plo);
  for (int half = 1; half <= 32; half <<= 1)
    pow_level<<<dim3(16, half), 256, 0, stream>>>(Pw, Phi, Plo, half);
  make_K<<<64, 256, 0, stream>>>(Pw, dB, Kf, Khi, Klo);
  finals<<<dim3(NCH, BATCH), 256, 0, stream>>>(Kf, u, G0);

  if (ws_size >= NEED_KS) {
    unsigned short* Sqh = (unsigned short*)(ws + 43122688); // 640 KB: M^2,4,8,16,32 hi
    unsigned short* Sql = (unsigned short*)(ws + 43778048); // 640 KB: lo
    float* G1 = (float*)(ws + 0);                           // aliases Pw slots 0..15 (dead by now)
    // fp32 squares go to Pw slots 56..60 (only slot 63 = dA^64 still needed)
    float* S[6];
    S[0] = Pw + (size_t)63 * 65536;                         // M = dA^64
    for (int d = 1; d <= 5; ++d) S[d] = Pw + (size_t)(55 + d) * 65536;
    for (int d = 0; d < 5; ++d)
      sq_mm<<<16, 256, 0, stream>>>(S[d], S[d + 1], Sqh + (size_t)d * 65536, Sql + (size_t)d * 65536);

    // Kogge-Stone: G0 ->L0-> G1 ->L1-> G0 ... ends in G0 after 6 levels
    const unsigned short* Mh0 = Phi + (size_t)63 * 65536;
    const unsigned short* Ml0 = Plo + (size_t)63 * 65536;
    ks_level<<<64, 256, 0, stream>>>(G0, G1, Mh0, Ml0, 64);
    ks_level<<<64, 256, 0, stream>>>(G1, G0, Sqh + 0 * 65536, Sql + 0 * 65536, 128);
    ks_level<<<64, 256, 0, stream>>>(G0, G1, Sqh + 1 * 65536, Sql + 1 * 65536, 256);
    ks_level<<<64, 256, 0, stream>>>(G1, G0, Sqh + 2 * 65536, Sql + 2 * 65536, 512);
    ks_level<<<64, 256, 0, stream>>>(G0, G1, Sqh + 3 * 65536, Sql + 3 * 65536, 1024);
    ks_level<<<64, 256, 0, stream>>>(G1, G0, Sqh + 4 * 65536, Sql + 4 * 65536, 2048);
    split_carr<<<NCH, 256, 0, stream>>>(G0, shi, slo);
  } else if (ws_size >= NEED_R1) {
    float* MT = (float*)(ws + 43122688);                    // 256 KB
    make_MT<<<256, 256, 0, stream>>>(Pw, MT);
    scan<<<BATCH, 512, 0, stream>>>(MT, G0, shi, slo);
  } else {
    return; // insufficient workspace (not expected; R1 proved >= NEED_R1)
  }

  main_gemm<<<dim3(64, 64), 256, 0, stream>>>(shi, slo, Phi, Plo, Khi, Klo, uT, out);
}

// Round 4
// 491.440 us; speedup vs baseline: 1.0660x; 1.0660x over previous
//
#include <hip/hip_runtime.h>
#include <hip/hip_bf16.h>
#include <stdint.h>

// HiPPO-LegT LTI scan: c_t = dA c_{t-1} + dB u_t, out = all c_t. N=256, L=4096, B=64.
//   c[k*64+dt] = dA^{dt+1} . s_k  +  sum_{p<=dt} (dA^p dB) . u[k*64+dt-p]   (main_gemm, MFMA)
//   s_k via Kogge-Stone over chunk finals (6 MFMA GEMM levels, full-chip 64x64 tiles).
// All fp32 data; MFMA operands split bf16 hi/lo (3-MFMA products, rel err ~2^-17).

#define N 256
#define LSEQ 4096
#define BATCH 64
#define TCH 64
#define NCH 64

using bf16x8 = __attribute__((ext_vector_type(8))) __bf16;
using f32x4  = __attribute__((ext_vector_type(4))) float;

__device__ __forceinline__ unsigned short f2bf(float f) {
  uint32_t x = __builtin_bit_cast(uint32_t, f);
  uint32_t r = x + 0x7fffu + ((x >> 16) & 1u);
  return (unsigned short)(r >> 16);
}
__device__ __forceinline__ float bf2f(unsigned short h) {
  uint32_t x = ((uint32_t)h) << 16;
  return __builtin_bit_cast(float, x);
}

// LDS swizzle for bf16 tiles with 32-short (64 B) rows, 4 chunks of 8 shorts:
// chunk c at row r lives at chunk (c ^ ((r>>1)&3)). 16-row b128 reads hit each
// bank-quad exactly 2x (free); staged writes are quad-uniform.
__device__ __forceinline__ int swz(int r, int c) { return r * 32 + ((c ^ ((r >> 1) & 3)) << 3); }

// prep0: bid<64 -> transpose u (L x B) into uT (B x L); bid>=64 -> copy dA into power
// slot 0 (dA^1) and write its bf16 hi/lo split.
__global__ __launch_bounds__(256) void prep0(const float* __restrict__ u,
                                             const float* __restrict__ dA,
                                             float* __restrict__ uT,
                                             float* __restrict__ Pw,
                                             unsigned short* __restrict__ Phi,
                                             unsigned short* __restrict__ Plo) {
  __shared__ float tile[64][65];
  int bid = blockIdx.x, tid = threadIdx.x;
  if (bid < 64) {
    int t0 = bid * 64;
    #pragma unroll
    for (int q = 0; q < 16; ++q) {
      int e = q * 256 + tid;
      int tt = e >> 6, b = e & 63;
      tile[b][tt] = u[(size_t)(t0 + tt) * 64 + b];
    }
    __syncthreads();
    #pragma unroll
    for (int q = 0; q < 16; ++q) {
      int e = q * 256 + tid;
      int b = e >> 6, tt = e & 63;
      uT[(size_t)b * 4096 + t0 + tt] = tile[b][tt];
    }
  } else {
    int base = (bid - 64) * 1024 + tid * 4;
    float4 v = *(const float4*)&dA[base];
    *(float4*)&Pw[base] = v;
    float vv[4] = {v.x, v.y, v.z, v.w};
    #pragma unroll
    for (int q = 0; q < 4; ++q) {
      unsigned short h = f2bf(vv[q]);
      Phi[base + q] = h;
      Plo[base + q] = f2bf(vv[q] - bf2f(h));
    }
  }
}

// pow_level: for q=1..half: P[half+q] = P[q] @ P[half] (slots are m-1). fp32 + hi/lo.
// 64x64 tile per block; transposed-A LDS staging, float4 outer products.
__global__ __launch_bounds__(256) void pow_level(float* __restrict__ Pw,
                                                 unsigned short* __restrict__ Phi,
                                                 unsigned short* __restrict__ Plo,
                                                 int half) {
  __shared__ float At[16][68];
  __shared__ float Bs[16][68];
  int q = blockIdx.y + 1;
  const float* A = Pw + (size_t)(q - 1) * 65536;
  const float* B = Pw + (size_t)(half - 1) * 65536;
  size_t co = (size_t)(half + q - 1) * 65536;
  int bx = blockIdx.x;
  int gr0 = (bx >> 2) * 64, gc0 = (bx & 3) * 64;
  int tid = threadIdx.x;
  int ty = tid >> 4, tx = tid & 15;

  float acc[4][4];
  #pragma unroll
  for (int r = 0; r < 4; ++r)
    #pragma unroll
    for (int c = 0; c < 4; ++c) acc[r][c] = 0.f;

  int ra = tid >> 2, ka4 = (tid & 3) << 2;
  int kb = tid >> 4, cb4 = (tid & 15) << 2;
  for (int k0 = 0; k0 < 256; k0 += 16) {
    float4 va = *(const float4*)&A[(size_t)(gr0 + ra) * 256 + k0 + ka4];
    At[ka4 + 0][ra] = va.x; At[ka4 + 1][ra] = va.y;
    At[ka4 + 2][ra] = va.z; At[ka4 + 3][ra] = va.w;
    *(float4*)&Bs[kb][cb4] = *(const float4*)&B[(size_t)(k0 + kb) * 256 + gc0 + cb4];
    __syncthreads();
    #pragma unroll
    for (int kk = 0; kk < 16; ++kk) {
      float4 a4 = *(const float4*)&At[kk][ty << 2];
      float4 b4 = *(const float4*)&Bs[kk][tx << 2];
      acc[0][0] += a4.x * b4.x; acc[0][1] += a4.x * b4.y; acc[0][2] += a4.x * b4.z; acc[0][3] += a4.x * b4.w;
      acc[1][0] += a4.y * b4.x; acc[1][1] += a4.y * b4.y; acc[1][2] += a4.y * b4.z; acc[1][3] += a4.y * b4.w;
      acc[2][0] += a4.z * b4.x; acc[2][1] += a4.z * b4.y; acc[2][2] += a4.z * b4.z; acc[2][3] += a4.z * b4.w;
      acc[3][0] += a4.w * b4.x; acc[3][1] += a4.w * b4.y; acc[3][2] += a4.w * b4.z; acc[3][3] += a4.w * b4.w;
    }
    __syncthreads();
  }
  #pragma unroll
  for (int r = 0; r < 4; ++r)
    #pragma unroll
    for (int c = 0; c < 4; ++c) {
      size_t idx = co + (size_t)(gr0 + ty * 4 + r) * 256 + gc0 + tx * 4 + c;
      float v = acc[r][c];
      Pw[idx] = v;
      unsigned short h = f2bf(v);
      Phi[idx] = h;
      Plo[idx] = f2bf(v - bf2f(h));
    }
}

// sq_mm: C = A @ A (256x256 fp32) -> fp32 C + bf16 hi/lo. Grid 16 blocks, same scheme.
__global__ __launch_bounds__(256) void sq_mm(const float* __restrict__ A,
                                             float* __restrict__ C,
                                             unsigned short* __restrict__ Chi,
                                             unsigned short* __restrict__ Clo) {
  __shared__ float At[16][68];
  __shared__ float Bs[16][68];
  int bx = blockIdx.x;
  int gr0 = (bx >> 2) * 64, gc0 = (bx & 3) * 64;
  int tid = threadIdx.x;
  int ty = tid >> 4, tx = tid & 15;

  float acc[4][4];
  #pragma unroll
  for (int r = 0; r < 4; ++r)
    #pragma unroll
    for (int c = 0; c < 4; ++c) acc[r][c] = 0.f;

  int ra = tid >> 2, ka4 = (tid & 3) << 2;
  int kb = tid >> 4, cb4 = (tid & 15) << 2;
  for (int k0 = 0; k0 < 256; k0 += 16) {
    float4 va = *(const float4*)&A[(size_t)(gr0 + ra) * 256 + k0 + ka4];
    At[ka4 + 0][ra] = va.x; At[ka4 + 1][ra] = va.y;
    At[ka4 + 2][ra] = va.z; At[ka4 + 3][ra] = va.w;
    *(float4*)&Bs[kb][cb4] = *(const float4*)&A[(size_t)(k0 + kb) * 256 + gc0 + cb4];
    __syncthreads();
    #pragma unroll
    for (int kk = 0; kk < 16; ++kk) {
      float4 a4 = *(const float4*)&At[kk][ty << 2];
      float4 b4 = *(const float4*)&Bs[kk][tx << 2];
      acc[0][0] += a4.x * b4.x; acc[0][1] += a4.x * b4.y; acc[0][2] += a4.x * b4.z; acc[0][3] += a4.x * b4.w;
      acc[1][0] += a4.y * b4.x; acc[1][1] += a4.y * b4.y; acc[1][2] += a4.y * b4.z; acc[1][3] += a4.y * b4.w;
      acc[2][0] += a4.z * b4.x; acc[2][1] += a4.z * b4.y; acc[2][2] += a4.z * b4.z; acc[2][3] += a4.z * b4.w;
      acc[3][0] += a4.w * b4.x; acc[3][1] += a4.w * b4.y; acc[3][2] += a4.w * b4.z; acc[3][3] += a4.w * b4.w;
    }
    __syncthreads();
  }
  #pragma unroll
  for (int r = 0; r < 4; ++r)
    #pragma unroll
    for (int c = 0; c < 4; ++c) {
      size_t idx = (size_t)(gr0 + ty * 4 + r) * 256 + gc0 + tx * 4 + c;
      float v = acc[r][c];
      C[idx] = v;
      unsigned short h = f2bf(v);
      Chi[idx] = h;
      Clo[idx] = f2bf(v - bf2f(h));
    }
}

// make_K: K[p] = dA^p dB (K[0]=dB).
__global__ __launch_bounds__(256) void make_K(const float* __restrict__ Pw,
                                              const float* __restrict__ dB,
                                              float* __restrict__ Kf,
                                              unsigned short* __restrict__ Khi,
                                              unsigned short* __restrict__ Klo) {
  int p = blockIdx.x, tid = threadIdx.x, lane = tid & 63, w = tid >> 6;
  if (p == 0) {
    float v = dB[tid];
    Kf[tid] = v;
    unsigned short h = f2bf(v);
    Khi[tid] = h;
    Klo[tid] = f2bf(v - bf2f(h));
    return;
  }
  const float* M = Pw + (size_t)(p - 1) * 65536;
  float d0 = dB[lane], d1 = dB[lane + 64], d2 = dB[lane + 128], d3 = dB[lane + 192];
  for (int ii = 0; ii < 64; ++ii) {
    int i = w * 64 + ii;
    const float* row = M + (size_t)i * 256;
    float acc = row[lane] * d0 + row[lane + 64] * d1 + row[lane + 128] * d2 + row[lane + 192] * d3;
    #pragma unroll
    for (int off = 32; off; off >>= 1) acc += __shfl_xor(acc, off, 64);
    if (lane == 0) {
      Kf[p * 256 + i] = acc;
      unsigned short h = f2bf(acc);
      Khi[p * 256 + i] = h;
      Klo[p * 256 + i] = f2bf(acc - bf2f(h));
    }
  }
}

// make_MT (fallback path only)
__global__ __launch_bounds__(256) void make_MT(const float* __restrict__ Pw,
                                               float* __restrict__ MT) {
  int j = blockIdx.x, i = threadIdx.x;
  MT[(size_t)j * 256 + i] = Pw[(size_t)63 * 65536 + (size_t)i * 256 + j];
}

// finals: G0[k][b][i] = sum_p K[p][i]*u[k*64+63-p][b]
__global__ __launch_bounds__(256) void finals(const float* __restrict__ K,
                                              const float* __restrict__ u,
                                              float* __restrict__ f) {
  int k = blockIdx.x, b = blockIdx.y, i = threadIdx.x;
  float acc = 0.f;
  int ubase = (k * TCH + 63) * BATCH + b;
  #pragma unroll 8
  for (int p = 0; p < TCH; ++p)
    acc += K[p * N + i] * u[ubase - p * BATCH];
  f[(k * BATCH + b) * N + i] = acc;
}

// ks_level: one Kogge-Stone level, 64x64 tiles over full chip (256 blocks).
// Gout[m] = Gin[m] + Gin[m-shift] @ M^T  (B-frag = M row-major [i][k]).
// FINAL level writes the chunk-shifted hi/lo carries directly: s[k] = G[k-1].
template <int FINAL>
__global__ __launch_bounds__(256) void ks_level(const float* __restrict__ Gin,
                                                float* __restrict__ Gout,
                                                const unsigned short* __restrict__ Mh,
                                                const unsigned short* __restrict__ Ml,
                                                int shift,
                                                unsigned short* __restrict__ shi,
                                                unsigned short* __restrict__ slo) {
  __shared__ __align__(16) unsigned short Ah[64 * 32], Al[64 * 32], Bh[64 * 32], Bl[64 * 32];
  int bx = blockIdx.x;
  int kb0 = (bx >> 2) * 64, i0 = (bx & 3) * 64;
  int tid = threadIdx.x, lane = tid & 63, wid = tid >> 6;
  int wr = wid >> 1, wc = wid & 1;
  int rg = lane >> 4, cl = lane & 15;

  f32x4 acc[2][2];
  #pragma unroll
  for (int mf = 0; mf < 2; ++mf) {
    int m0 = kb0 + wr * 32 + mf * 16 + rg * 4;
    #pragma unroll
    for (int nf = 0; nf < 2; ++nf) {
      int i = i0 + wc * 32 + nf * 16 + cl;
      #pragma unroll
      for (int r = 0; r < 4; ++r)
        acc[mf][nf][r] = Gin[(size_t)(m0 + r) * 256 + i];
    }
  }

  int sr = tid >> 2, kc = tid & 3;
  int sw = swz(sr, kc);
  for (int kt = 0; kt < 8; ++kt) {
    int srow = kb0 + sr - shift;
    if (srow >= 0) {
      const float* src = &Gin[(size_t)srow * 256 + kt * 32 + kc * 8];
      float4 v0 = *(const float4*)src;
      float4 v1 = *(const float4*)(src + 4);
      float vv[8] = {v0.x, v0.y, v0.z, v0.w, v1.x, v1.y, v1.z, v1.w};
      unsigned short hv[8], lv[8];
      #pragma unroll
      for (int e = 0; e < 8; ++e) {
        hv[e] = f2bf(vv[e]);
        lv[e] = f2bf(vv[e] - bf2f(hv[e]));
      }
      *(uint4*)&Ah[sw] = *(const uint4*)hv;
      *(uint4*)&Al[sw] = *(const uint4*)lv;
    } else {
      uint4 z = {0, 0, 0, 0};
      *(uint4*)&Ah[sw] = z;
      *(uint4*)&Al[sw] = z;
    }
    *(uint4*)&Bh[sw] = *(const uint4*)&Mh[(size_t)(i0 + sr) * 256 + kt * 32 + kc * 8];
    *(uint4*)&Bl[sw] = *(const uint4*)&Ml[(size_t)(i0 + sr) * 256 + kt * 32 + kc * 8];
    __syncthreads();

    int fr = lane & 15, kseg = lane >> 4;
    bf16x8 ah[2], al[2], bh[2], bl[2];
    #pragma unroll
    for (int mf = 0; mf < 2; ++mf) {
      int row = wr * 32 + mf * 16 + fr;
      ah[mf] = *(const bf16x8*)&Ah[swz(row, kseg)];
      al[mf] = *(const bf16x8*)&Al[swz(row, kseg)];
    }
    #pragma unroll
    for (int nf = 0; nf < 2; ++nf) {
      int row = wc * 32 + nf * 16 + fr;
      bh[nf] = *(const bf16x8*)&Bh[swz(row, kseg)];
      bl[nf] = *(const bf16x8*)&Bl[swz(row, kseg)];
    }
    #pragma unroll
    for (int mf = 0; mf < 2; ++mf)
      #pragma unroll
      for (int nf = 0; nf < 2; ++nf) {
        acc[mf][nf] = __builtin_amdgcn_mfma_f32_16x16x32_bf16(ah[mf], bh[nf], acc[mf][nf], 0, 0, 0);
        acc[mf][nf] = __builtin_amdgcn_mfma_f32_16x16x32_bf16(ah[mf], bl[nf], acc[mf][nf], 0, 0, 0);
        acc[mf][nf] = __builtin_amdgcn_mfma_f32_16x16x32_bf16(al[mf], bh[nf], acc[mf][nf], 0, 0, 0);
      }
    __syncthreads();
  }

  #pragma unroll
  for (int mf = 0; mf < 2; ++mf) {
    int m0 = kb0 + wr * 32 + mf * 16 + rg * 4;
    #pragma unroll
    for (int nf = 0; nf < 2; ++nf) {
      int i = i0 + wc * 32 + nf * 16 + cl;
      #pragma unroll
      for (int r = 0; r < 4; ++r) {
        if (FINAL) {
          int tm = m0 + r + 64;  // s chunk k gets G[k-1]
          if (tm < 4096) {
            float v = acc[mf][nf][r];
            unsigned short h = f2bf(v);
            shi[(size_t)tm * 256 + i] = h;
            slo[(size_t)tm * 256 + i] = f2bf(v - bf2f(h));
          }
        } else {
          Gout[(size_t)(m0 + r) * 256 + i] = acc[mf][nf][r];
        }
      }
    }
  }
  if (FINAL && kb0 == 0) {
    for (int e = tid; e < 4096; e += 256) {
      size_t o = (size_t)(e >> 6) * 256 + i0 + (e & 63);
      shi[o] = 0;
      slo[o] = 0;
    }
  }
}

// scan (fallback path only): serial fp32 carry scan.
__global__ __launch_bounds__(512) void scan(const float* __restrict__ MT,
                                            const float* __restrict__ f,
                                            unsigned short* __restrict__ shi,
                                            unsigned short* __restrict__ slo) {
  __shared__ float sbuf[256];
  __shared__ float psum[256];
  int b = blockIdx.x, tid = threadIdx.x;
  int i = tid & 255, jh = tid >> 8;
  if (tid < 256) sbuf[i] = 0.f;
  __syncthreads();
  for (int k = 0; k < NCH; ++k) {
    if (jh == 0) {
      float v = sbuf[i];
      unsigned short h = f2bf(v);
      size_t o = (size_t)(k * BATCH + b) * 256 + i;
      shi[o] = h;
      slo[o] = f2bf(v - bf2f(h));
    }
    if (k == NCH - 1) break;
    float acc = 0.f;
    int j0 = jh * 128;
    #pragma unroll 8
    for (int j = 0; j < 128; ++j)
      acc += MT[(size_t)(j0 + j) * 256 + i] * sbuf[j0 + j];
    __syncthreads();
    if (jh == 1) psum[i] = acc;
    __syncthreads();
    if (jh == 0) sbuf[i] = acc + psum[i] + f[(size_t)(k * BATCH + b) * 256 + i];
    __syncthreads();
  }
}

// main_gemm: out[k*64+dt][b][i] = sum_j P[dt+1][i][j] s_k[b][j] + sum_{p<=dt} K[p][i] u[kT+dt-p][b]
// Swizzled 64B-stride LDS (bank-conflict-free), 3 blocks/CU.
__global__ __launch_bounds__(256, 3) void main_gemm(const unsigned short* __restrict__ shi,
                                                    const unsigned short* __restrict__ slo,
                                                    const unsigned short* __restrict__ Phi,
                                                    const unsigned short* __restrict__ Plo,
                                                    const unsigned short* __restrict__ Khi,
                                                    const unsigned short* __restrict__ Klo,
                                                    const float* __restrict__ uT,
                                                    float* __restrict__ out) {
  __shared__ __align__(16) unsigned short Ah[128 * 32], Al[128 * 32], Bh[128 * 32], Bl[128 * 32];
  int dt = blockIdx.y;
  int x = blockIdx.x;
  int it = x >> 5, kbt = x & 31;
  int kb0 = kbt * 128, i0 = it * 128;
  int tid = threadIdx.x;
  int lane = tid & 63, wid = tid >> 6;
  int wr = wid >> 1, wc = wid & 1;

  f32x4 acc[4][4];
  #pragma unroll
  for (int mf = 0; mf < 4; ++mf)
    #pragma unroll
    for (int nf = 0; nf < 4; ++nf)
      #pragma unroll
      for (int r = 0; r < 4; ++r) acc[mf][nf][r] = 0.f;

  const unsigned short* PhiD = Phi + (size_t)dt * 65536;
  const unsigned short* PloD = Plo + (size_t)dt * 65536;
  int nkt = (dt >= 32) ? 10 : 9;

  for (int kt = 0; kt < nkt; ++kt) {
    int r = tid >> 1, h = tid & 1;
    if (kt < 8) {
      int co = kt * 32 + h * 16;
      const unsigned short* p1 = shi + (size_t)(kb0 + r) * 256 + co;
      const unsigned short* p2 = slo + (size_t)(kb0 + r) * 256 + co;
      const unsigned short* p3 = PhiD + (size_t)(i0 + r) * 256 + co;
      const unsigned short* p4 = PloD + (size_t)(i0 + r) * 256 + co;
      int sw0 = swz(r, 2 * h);
      int sw1 = swz(r, 2 * h + 1);
      *(uint4*)&Ah[sw0] = *(const uint4*)p1;
      *(uint4*)&Ah[sw1] = *(const uint4*)(p1 + 8);
      *(uint4*)&Al[sw0] = *(const uint4*)p2;
      *(uint4*)&Al[sw1] = *(const uint4*)(p2 + 8);
      *(uint4*)&Bh[sw0] = *(const uint4*)p3;
      *(uint4*)&Bh[sw1] = *(const uint4*)(p3 + 8);
      *(uint4*)&Bl[sw0] = *(const uint4*)p4;
      *(uint4*)&Bl[sw1] = *(const uint4*)(p4 + 8);
    } else {
      int p0 = (kt - 8) * 32;
      int kk = (kb0 + r) >> 6, b = (kb0 + r) & 63;
      const float* ub2 = uT + (size_t)b * 4096 + kk * 64 + dt;
      #pragma unroll
      for (int qq = 0; qq < 16; ++qq) {
        int pp = h * 16 + qq;
        int sh = p0 + pp;
        float v = (sh <= dt) ? ub2[-sh] : 0.f;
        unsigned short hv = f2bf(v);
        int idx = swz(r, pp >> 3) + (pp & 7);
        Ah[idx] = hv;
        Al[idx] = f2bf(v - bf2f(hv));
      }
      int n = tid & 127, ph = tid >> 7;
      #pragma unroll
      for (int qq = 0; qq < 16; ++qq) {
        int pp = ph * 16 + qq;
        int idx = swz(n, pp >> 3) + (pp & 7);
        Bh[idx] = Khi[(p0 + pp) * 256 + i0 + n];
        Bl[idx] = Klo[(p0 + pp) * 256 + i0 + n];
      }
    }
    __syncthreads();

    int kseg = lane >> 4, fr = lane & 15;
    bf16x8 ah[4], al[4], bh[4], bl[4];
    #pragma unroll
    for (int mf = 0; mf < 4; ++mf) {
      int row = wr * 64 + mf * 16 + fr;
      ah[mf] = *(const bf16x8*)&Ah[swz(row, kseg)];
      al[mf] = *(const bf16x8*)&Al[swz(row, kseg)];
    }
    #pragma unroll
    for (int nf = 0; nf < 4; ++nf) {
      int row = wc * 64 + nf * 16 + fr;
      bh[nf] = *(const bf16x8*)&Bh[swz(row, kseg)];
      bl[nf] = *(const bf16x8*)&Bl[swz(row, kseg)];
    }
    #pragma unroll
    for (int mf = 0; mf < 4; ++mf)
      #pragma unroll
      for (int nf = 0; nf < 4; ++nf) {
        acc[mf][nf] = __builtin_amdgcn_mfma_f32_16x16x32_bf16(ah[mf], bh[nf], acc[mf][nf], 0, 0, 0);
        acc[mf][nf] = __builtin_amdgcn_mfma_f32_16x16x32_bf16(ah[mf], bl[nf], acc[mf][nf], 0, 0, 0);
        acc[mf][nf] = __builtin_amdgcn_mfma_f32_16x16x32_bf16(al[mf], bh[nf], acc[mf][nf], 0, 0, 0);
      }
    __syncthreads();
  }

  int rg = lane >> 4, cl = lane & 15;
  #pragma unroll
  for (int mf = 0; mf < 4; ++mf) {
    int kbrow_base = kb0 + wr * 64 + mf * 16 + rg * 4;
    #pragma unroll
    for (int nf = 0; nf < 4; ++nf) {
      int i = i0 + wc * 64 + nf * 16 + cl;
      #pragma unroll
      for (int r = 0; r < 4; ++r) {
        int kbrow = kbrow_base + r;
        int k = kbrow >> 6, b = kbrow & 63;
        size_t t = (size_t)(k * 64 + dt);
        out[(t * 64 + b) * 256 + i] = acc[mf][nf][r];
      }
    }
  }
}

// ======================= HOST =======================

extern "C" void kernel_launch(void* const* d_in, const int* in_sizes, int n_in,
                              void* d_out, int out_size, void* d_ws, size_t ws_size,
                              hipStream_t stream) {
  (void)in_sizes; (void)n_in; (void)out_size;
  const float* u  = (const float*)d_in[0];
  const float* dA = (const float*)d_in[1];
  const float* dB = (const float*)d_in[2];
  float* out = (float*)d_out;
  char* ws = (char*)d_ws;

  float*          Pw  = (float*)(ws + 0);                  // 16 MB: dA^1..dA^64 (slot m-1)
  unsigned short* Phi = (unsigned short*)(ws + 16777216);  // 8 MB
  unsigned short* Plo = (unsigned short*)(ws + 25165824);  // 8 MB
  float*          Kf  = (float*)(ws + 33554432);           // 64 KB
  unsigned short* Khi = (unsigned short*)(ws + 33619968);  // 32 KB
  unsigned short* Klo = (unsigned short*)(ws + 33652736);  // 32 KB
  unsigned short* shi = (unsigned short*)(ws + 33685504);  // 2 MB
  unsigned short* slo = (unsigned short*)(ws + 35782656);  // 2 MB
  float*          G0  = (float*)(ws + 37879808);           // 4 MB
  float*          uT  = (float*)(ws + 42074112);           // 1 MB

  const size_t NEED_KS = 44433408;
  const size_t NEED_R1 = 43384832;

  prep0<<<128, 256, 0, stream>>>(u, dA, uT, Pw, Phi, Plo);
  for (int half = 1; half <= 32; half <<= 1)
    pow_level<<<dim3(16, half), 256, 0, stream>>>(Pw, Phi, Plo, half);
  make_K<<<64, 256, 0, stream>>>(Pw, dB, Kf, Khi, Klo);
  finals<<<dim3(NCH, BATCH), 256, 0, stream>>>(Kf, u, G0);

  if (ws_size >= NEED_KS) {
    unsigned short* Sqh = (unsigned short*)(ws + 43122688); // 640 KB: M^2,4,8,16,32 hi
    unsigned short* Sql = (unsigned short*)(ws + 43778048); // 640 KB: lo
    float* G1 = (float*)(ws + 0);                           // aliases Pw slots 0..15 (dead)
    float* S[6];
    S[0] = Pw + (size_t)63 * 65536;                         // M = dA^64
    for (int d = 1; d <= 5; ++d) S[d] = Pw + (size_t)(55 + d) * 65536;
    for (int d = 0; d < 5; ++d)
      sq_mm<<<16, 256, 0, stream>>>(S[d], S[d + 1], Sqh + (size_t)d * 65536, Sql + (size_t)d * 65536);

    const unsigned short* Mh0 = Phi + (size_t)63 * 65536;
    const unsigned short* Ml0 = Plo + (size_t)63 * 65536;
    ks_level<0><<<256, 256, 0, stream>>>(G0, G1, Mh0, Ml0, 64, nullptr, nullptr);
    ks_level<0><<<256, 256, 0, stream>>>(G1, G0, Sqh + 0 * 65536, Sql + 0 * 65536, 128, nullptr, nullptr);
    ks_level<0><<<256, 256, 0, stream>>>(G0, G1, Sqh + 1 * 65536, Sql + 1 * 65536, 256, nullptr, nullptr);
    ks_level<0><<<256, 256, 0, stream>>>(G1, G0, Sqh + 2 * 65536, Sql + 2 * 65536, 512, nullptr, nullptr);
    ks_level<0><<<256, 256, 0, stream>>>(G0, G1, Sqh + 3 * 65536, Sql + 3 * 65536, 1024, nullptr, nullptr);
    ks_level<1><<<256, 256, 0, stream>>>(G1, nullptr, Sqh + 4 * 65536, Sql + 4 * 65536, 2048, shi, slo);
  } else if (ws_size >= NEED_R1) {
    float* MT = (float*)(ws + 43122688);                    // 256 KB
    make_MT<<<256, 256, 0, stream>>>(Pw, MT);
    scan<<<BATCH, 512, 0, stream>>>(MT, G0, shi, slo);
  } else {
    return;
  }

  main_gemm<<<dim3(64, 64), 256, 0, stream>>>(shi, slo, Phi, Plo, Khi, Klo, uT, out);
}